// Round 5
// baseline (244.163 us; speedup 1.0000x reference)
//
#include <hip/hip_runtime.h>
#include <hip/hip_bf16.h>

// SingleHeadAttention: B=4, S=4096, H=1024, D=64. fp32 I/O, bf16 MFMA compute.
//
// k0: convert Wq/Wk/Wv/Wo fp32 -> bf16 (ws)
// k1: fused QKV proj: 1-wave blocks, 16-row tiles, depth-2 a-prefetch,
//     12 MFMA/k-step; x read once. V stored TRANSPOSED Vt[b][d][s].
// k2: split-K causal flash: 512-key chunks (CHT=8), reg-prefetch double buffer
// k3: merge partials (qb >= 8)
// k4: Y = O @ Wo^T (fp32 out)

typedef __attribute__((ext_vector_type(8))) __bf16 bf16x8;
typedef __attribute__((ext_vector_type(4))) float f32x4;

#define BATCH 4
#define SEQ   4096
#define HID   1024
#define HDIM  64
#define CHT   8           // 64-key tiles per split-K chunk
#define NCMAX 8           // max chunks per Q-tile

__device__ __forceinline__ unsigned short f2bf(float f) {
  unsigned u = __builtin_bit_cast(unsigned, f);
  u += 0x7fffu + ((u >> 16) & 1u);          // RTN
  return (unsigned short)(u >> 16);
}
__device__ __forceinline__ float bf2f(unsigned short u) {
  unsigned v = ((unsigned)u) << 16;
  return __builtin_bit_cast(float, v);
}
__device__ __forceinline__ __bf16 f2bf16(float f) {
  unsigned short us = f2bf(f);
  return __builtin_bit_cast(__bf16, us);
}
__device__ __forceinline__ bf16x8 pack8(f32x4 a, f32x4 b) {
  bf16x8 r;
  r[0] = f2bf16(a[0]); r[1] = f2bf16(a[1]); r[2] = f2bf16(a[2]); r[3] = f2bf16(a[3]);
  r[4] = f2bf16(b[0]); r[5] = f2bf16(b[1]); r[6] = f2bf16(b[2]); r[7] = f2bf16(b[3]);
  return r;
}

// ---------------- k0: weight conversion ----------------
__global__ __launch_bounds__(256) void convert_w(
    const float* __restrict__ Wq, const float* __restrict__ Wk,
    const float* __restrict__ Wv, const float* __restrict__ Wo,
    unsigned short* __restrict__ q, unsigned short* __restrict__ k,
    unsigned short* __restrict__ v, unsigned short* __restrict__ o) {
  const int gid = blockIdx.x * 256 + threadIdx.x;
  const int mat = gid >> 16, idx = gid & 0xFFFF;
  const float* s = (mat == 0) ? Wq : (mat == 1) ? Wk : (mat == 2) ? Wv : Wo;
  unsigned short* d = (mat == 0) ? q : (mat == 1) ? k : (mat == 2) ? v : o;
  d[idx] = f2bf(s[idx]);
}

// ---------------- k1: fused QKV projection ----------------
// grid 1024 x 64 threads: one wave per 16-row tile; computes q,k,v together.
__global__ __launch_bounds__(64) void qkv_proj(
    const float* __restrict__ x,
    const unsigned short* __restrict__ Wqb,
    const unsigned short* __restrict__ Wkb,
    const unsigned short* __restrict__ Wvb,
    unsigned short* __restrict__ Q,
    unsigned short* __restrict__ K,
    unsigned short* __restrict__ Vt) {
  const int mb   = blockIdx.x;          // 16-row tile
  const int lane = threadIdx.x;
  const int quad = lane >> 4;
  const int l15  = lane & 15;
  const int row0 = mb * 16;

  const unsigned short* Ws[3] = {Wqb, Wkb, Wvb};

  f32x4 acc[3][4];
  const f32x4 zero = {0.f, 0.f, 0.f, 0.f};
#pragma unroll
  for (int z = 0; z < 3; ++z)
#pragma unroll
    for (int n = 0; n < 4; ++n) acc[z][n] = zero;

  const float* ap = x + (size_t)(row0 + l15) * HID + quad * 8;

  // depth-2 a-frag prefetch pipeline
  f32x4 af[2][2];
  af[0][0] = *reinterpret_cast<const f32x4*>(ap);
  af[0][1] = *reinterpret_cast<const f32x4*>(ap + 4);
  af[1][0] = *reinterpret_cast<const f32x4*>(ap + 32);
  af[1][1] = *reinterpret_cast<const f32x4*>(ap + 36);

  int slot = 0;
  for (int kk = 0; kk < HID; kk += 32) {
    bf16x8 a = pack8(af[slot][0], af[slot][1]);
    if (kk + 64 < HID) {                 // refill this slot for kk+64
      af[slot][0] = *reinterpret_cast<const f32x4*>(ap + kk + 64);
      af[slot][1] = *reinterpret_cast<const f32x4*>(ap + kk + 68);
    }
    slot ^= 1;
#pragma unroll
    for (int z = 0; z < 3; ++z)
#pragma unroll
      for (int n = 0; n < 4; ++n) {
        bf16x8 b = *reinterpret_cast<const bf16x8*>(Ws[z] + (size_t)(n * 16 + l15) * HID + kk + quad * 8);
        acc[z][n] = __builtin_amdgcn_mfma_f32_16x16x32_bf16(a, b, acc[z][n], 0, 0, 0);
      }
  }

  // Q, K row-major
#pragma unroll
  for (int z = 0; z < 2; ++z) {
    unsigned short* Out = (z == 0) ? Q : K;
#pragma unroll
    for (int n = 0; n < 4; ++n)
#pragma unroll
      for (int r = 0; r < 4; ++r) {
        const int row = row0 + quad * 4 + r;
        const int col = n * 16 + l15;
        Out[(size_t)row * HDIM + col] = f2bf(acc[z][n][r]);
      }
  }
  // V transposed: Vt[b][dim][seq]
#pragma unroll
  for (int n = 0; n < 4; ++n)
#pragma unroll
    for (int r = 0; r < 4; ++r) {
      const int row = row0 + quad * 4 + r;        // global seq index
      const int col = n * 16 + l15;               // dim
      const int bb = row >> 12, sl = row & 4095;
      Vt[(size_t)bb * HDIM * SEQ + (size_t)col * SEQ + sl] = f2bf(acc[2][n][r]);
    }
}

// ---------------- k2: split-K causal flash, reg-prefetch dbuf ----------------
#define LSTR 72   // 64 + 8 pad (16B-aligned rows)

__global__ __launch_bounds__(256) void flash_splitk(
    const unsigned short* __restrict__ Qg,
    const unsigned short* __restrict__ Kg,
    const unsigned short* __restrict__ Vt,
    unsigned short* __restrict__ Og,
    unsigned short* __restrict__ Opart,
    float2* __restrict__ Ml) {
  const int qb = blockIdx.x;
  const int b  = blockIdx.y;
  const int c  = blockIdx.z;
  const int nc = (qb >> 3) + 1;          // ceil((qb+1)/CHT) for CHT=8
  if (c >= nc) return;
  const int j0 = c * CHT;
  const int j1 = min(j0 + CHT, qb + 1);

  const int tid  = threadIdx.x;
  const int lane = tid & 63;
  const int wave = tid >> 6;
  const int quad = lane >> 4;
  const int l15  = lane & 15;

  __shared__ unsigned short kt[64 * LSTR];       // K tile [key][dim]
  __shared__ unsigned short vt[64 * LSTR];       // V tile [dim][key]
  __shared__ unsigned short pt[4][16 * LSTR];    // per-wave P [qrow][key]

  const size_t base  = (size_t)b * SEQ * HDIM;
  const size_t baseT = (size_t)b * HDIM * SEQ;
  const int qrow0 = qb * 64 + wave * 16;

  bf16x8 aq[2];
  {
    const unsigned short* qp = Qg + base + (size_t)(qrow0 + l15) * HDIM + quad * 8;
    aq[0] = *reinterpret_cast<const bf16x8*>(qp);
    aq[1] = *reinterpret_cast<const bf16x8*>(qp + 32);
  }

  f32x4 o[4];
  const f32x4 zero = {0.f, 0.f, 0.f, 0.f};
#pragma unroll
  for (int n = 0; n < 4; ++n) o[n] = zero;
  float m_i[4], l_i[4];
#pragma unroll
  for (int r = 0; r < 4; ++r) { m_i[r] = -__builtin_inff(); l_i[r] = 0.f; }

  unsigned short* pw = pt[wave];
  const int srow = tid >> 2, sc0 = (tid & 3) * 16;   // staging coords
  const unsigned short* kb = Kg + base;
  const unsigned short* vb = Vt + baseT;

  // softmax scale folded into exp2: p = 2^(s*C - m*C),  C = 0.125*log2(e)
  const float C = 0.125f * 1.44269504f;

  // prologue: stage tile j0
  uint4 pk0, pk1, pv0, pv1;
  {
    const uint4* kp = reinterpret_cast<const uint4*>(kb + (size_t)(j0 * 64 + srow) * HDIM + sc0);
    pk0 = kp[0]; pk1 = kp[1];
    const uint4* vp = reinterpret_cast<const uint4*>(vb + (size_t)srow * SEQ + j0 * 64 + sc0);
    pv0 = vp[0]; pv1 = vp[1];
    *reinterpret_cast<uint4*>(&kt[srow * LSTR + sc0])     = pk0;
    *reinterpret_cast<uint4*>(&kt[srow * LSTR + sc0 + 8]) = pk1;
    *reinterpret_cast<uint4*>(&vt[srow * LSTR + sc0])     = pv0;
    *reinterpret_cast<uint4*>(&vt[srow * LSTR + sc0 + 8]) = pv1;
  }

  for (int j = j0; j < j1; ++j) {
    __syncthreads();                       // publish LDS tile j
    const bool pre = (j + 1 < j1);
    if (pre) {                             // issue loads for tile j+1 now
      const uint4* kp = reinterpret_cast<const uint4*>(kb + (size_t)((j + 1) * 64 + srow) * HDIM + sc0);
      pk0 = kp[0]; pk1 = kp[1];
      const uint4* vp = reinterpret_cast<const uint4*>(vb + (size_t)srow * SEQ + (j + 1) * 64 + sc0);
      pv0 = vp[0]; pv1 = vp[1];
    }

    f32x4 s[4];
#pragma unroll
    for (int n = 0; n < 4; ++n) s[n] = zero;
#pragma unroll
    for (int ks = 0; ks < 2; ++ks) {
#pragma unroll
      for (int n = 0; n < 4; ++n) {
        bf16x8 bk = *reinterpret_cast<const bf16x8*>(&kt[(n * 16 + l15) * LSTR + ks * 32 + quad * 8]);
        s[n] = __builtin_amdgcn_mfma_f32_16x16x32_bf16(aq[ks], bk, s[n], 0, 0, 0);
      }
    }

    if (j == qb) {                         // causal mask (raw-score units)
#pragma unroll
      for (int n = 0; n < 4; ++n) {
        const int col = n * 16 + l15;
#pragma unroll
        for (int r = 0; r < 4; ++r) {
          const int rowl = wave * 16 + quad * 4 + r;
          if (col > rowl) s[n][r] = -__builtin_inff();
        }
      }
    }

    float mnew[4], alpha[4], mC[4];
#pragma unroll
    for (int r = 0; r < 4; ++r) {
      float v = fmaxf(fmaxf(s[0][r], s[1][r]), fmaxf(s[2][r], s[3][r]));
#pragma unroll
      for (int off = 1; off < 16; off <<= 1) v = fmaxf(v, __shfl_xor(v, off, 64));
      mnew[r]  = fmaxf(m_i[r], v);
      alpha[r] = __builtin_amdgcn_exp2f((m_i[r] - mnew[r]) * C);
      mC[r]    = mnew[r] * C;
    }
    float p[4][4];
#pragma unroll
    for (int n = 0; n < 4; ++n)
#pragma unroll
      for (int r = 0; r < 4; ++r)
        p[n][r] = __builtin_amdgcn_exp2f(__builtin_fmaf(s[n][r], C, -mC[r]));
#pragma unroll
    for (int r = 0; r < 4; ++r) {
      float v = (p[0][r] + p[1][r]) + (p[2][r] + p[3][r]);
#pragma unroll
      for (int off = 1; off < 16; off <<= 1) v += __shfl_xor(v, off, 64);
      l_i[r] = l_i[r] * alpha[r] + v;
      m_i[r] = mnew[r];
    }
#pragma unroll
    for (int n = 0; n < 4; ++n)
#pragma unroll
      for (int r = 0; r < 4; ++r) o[n][r] *= alpha[r];

#pragma unroll
    for (int n = 0; n < 4; ++n)
#pragma unroll
      for (int r = 0; r < 4; ++r)
        pw[(quad * 4 + r) * LSTR + n * 16 + l15] = f2bf(p[n][r]);

#pragma unroll
    for (int ks = 0; ks < 2; ++ks) {
      bf16x8 ap = *reinterpret_cast<const bf16x8*>(&pw[l15 * LSTR + ks * 32 + quad * 8]);
#pragma unroll
      for (int n = 0; n < 4; ++n) {
        bf16x8 bv = *reinterpret_cast<const bf16x8*>(&vt[(n * 16 + l15) * LSTR + ks * 32 + quad * 8]);
        o[n] = __builtin_amdgcn_mfma_f32_16x16x32_bf16(ap, bv, o[n], 0, 0, 0);
      }
    }

    __syncthreads();                       // all waves done reading kt/vt
    if (pre) {                             // drain prefetch into LDS
      *reinterpret_cast<uint4*>(&kt[srow * LSTR + sc0])     = pk0;
      *reinterpret_cast<uint4*>(&kt[srow * LSTR + sc0 + 8]) = pk1;
      *reinterpret_cast<uint4*>(&vt[srow * LSTR + sc0])     = pv0;
      *reinterpret_cast<uint4*>(&vt[srow * LSTR + sc0 + 8]) = pv1;
    }
  }

  if (nc == 1) {
#pragma unroll
    for (int n = 0; n < 4; ++n)
#pragma unroll
      for (int r = 0; r < 4; ++r) {
        const int row = qrow0 + quad * 4 + r;
        const int col = n * 16 + l15;
        Og[base + (size_t)row * HDIM + col] = f2bf(o[n][r] / l_i[r]);
      }
  } else {
    const int slot = ((b * 64 + qb) << 3) + c;
#pragma unroll
    for (int n = 0; n < 4; ++n)
#pragma unroll
      for (int r = 0; r < 4; ++r) {
        const int rowl = wave * 16 + quad * 4 + r;
        const int col  = n * 16 + l15;
        Opart[(size_t)slot * 4096 + rowl * 64 + col] = f2bf(o[n][r]);
      }
    if (l15 == 0) {
#pragma unroll
      for (int r = 0; r < 4; ++r) {
        const int rowl = wave * 16 + quad * 4 + r;
        Ml[slot * 64 + rowl] = make_float2(m_i[r], l_i[r]);
      }
    }
  }
}

// ---------------- k3: merge split-K partials (qb >= 8) ----------------
__global__ __launch_bounds__(256) void merge_splitk(
    const unsigned short* __restrict__ Opart,
    const float2* __restrict__ Ml,
    unsigned short* __restrict__ Og) {
  const int qb = blockIdx.x;
  if (qb < CHT) return;
  const int b  = blockIdx.y;
  const int nc = (qb >> 3) + 1;
  const int row = threadIdx.x >> 2;
  const int cg  = (threadIdx.x & 3) * 16;
  const int slot0 = (b * 64 + qb) << 3;

  float m[NCMAX], l[NCMAX];
  float M = -__builtin_inff();
  for (int c = 0; c < nc; ++c) {
    float2 ml = Ml[(slot0 + c) * 64 + row];
    m[c] = ml.x; l[c] = ml.y;
    M = fmaxf(M, m[c]);
  }
  const float C = 0.125f * 1.44269504f;
  float L = 0.f, acc[16];
#pragma unroll
  for (int i = 0; i < 16; ++i) acc[i] = 0.f;
  for (int c = 0; c < nc; ++c) {
    const float w = __builtin_amdgcn_exp2f((m[c] - M) * C);
    L += w * l[c];
    const unsigned short* p = Opart + (size_t)(slot0 + c) * 4096 + row * 64 + cg;
    uint4 u0 = *reinterpret_cast<const uint4*>(p);
    uint4 u1 = *reinterpret_cast<const uint4*>(p + 8);
    const unsigned* uu = &u0.x;
#pragma unroll
    for (int i = 0; i < 4; ++i) {
      acc[2 * i]     += w * bf2f((unsigned short)(uu[i] & 0xFFFF));
      acc[2 * i + 1] += w * bf2f((unsigned short)(uu[i] >> 16));
    }
    const unsigned* vv = &u1.x;
#pragma unroll
    for (int i = 0; i < 4; ++i) {
      acc[8 + 2 * i]     += w * bf2f((unsigned short)(vv[i] & 0xFFFF));
      acc[8 + 2 * i + 1] += w * bf2f((unsigned short)(vv[i] >> 16));
    }
  }
  const float inv = 1.f / L;
  uint4 o0, o1;
  unsigned* po = &o0.x;
#pragma unroll
  for (int i = 0; i < 4; ++i)
    po[i] = (unsigned)f2bf(acc[2 * i] * inv) | ((unsigned)f2bf(acc[2 * i + 1] * inv) << 16);
  unsigned* p1 = &o1.x;
#pragma unroll
  for (int i = 0; i < 4; ++i)
    p1[i] = (unsigned)f2bf(acc[8 + 2 * i] * inv) | ((unsigned)f2bf(acc[8 + 2 * i + 1] * inv) << 16);
  unsigned short* dst = Og + (size_t)b * SEQ * HDIM + (size_t)(qb * 64 + row) * HDIM + cg;
  *reinterpret_cast<uint4*>(dst)     = o0;
  *reinterpret_cast<uint4*>(dst + 8) = o1;
}

// ---------------- k4: output projection Y = O @ Wo^T (fp32 out) ----------------
__global__ __launch_bounds__(256) void out_proj(
    const unsigned short* __restrict__ O,
    const unsigned short* __restrict__ Wob,
    float* __restrict__ Y) {
  const int nb   = blockIdx.x;
  const int mb   = blockIdx.y;
  const int lane = threadIdx.x & 63;
  const int wave = threadIdx.x >> 6;
  const int quad = lane >> 4;
  const int l15  = lane & 15;
  const int row0 = mb * 64 + wave * 16;

  f32x4 acc[4];
  const f32x4 zero = {0.f, 0.f, 0.f, 0.f};
#pragma unroll
  for (int n = 0; n < 4; ++n) acc[n] = zero;

  const unsigned short* op = O + (size_t)(row0 + l15) * HDIM + quad * 8;
  bf16x8 a0 = *reinterpret_cast<const bf16x8*>(op);
  bf16x8 a1 = *reinterpret_cast<const bf16x8*>(op + 32);
#pragma unroll
  for (int n = 0; n < 4; ++n) {
    const int col = nb * 64 + n * 16 + l15;
    const unsigned short* wp = Wob + (size_t)col * HDIM + quad * 8;
    bf16x8 b0 = *reinterpret_cast<const bf16x8*>(wp);
    bf16x8 b1 = *reinterpret_cast<const bf16x8*>(wp + 32);
    acc[n] = __builtin_amdgcn_mfma_f32_16x16x32_bf16(a0, b0, acc[n], 0, 0, 0);
    acc[n] = __builtin_amdgcn_mfma_f32_16x16x32_bf16(a1, b1, acc[n], 0, 0, 0);
  }
#pragma unroll
  for (int n = 0; n < 4; ++n)
#pragma unroll
    for (int r = 0; r < 4; ++r) {
      const int row = row0 + quad * 4 + r;
      const int col = nb * 64 + n * 16 + l15;
      Y[(size_t)row * HID + col] = acc[n][r];
    }
}

extern "C" void kernel_launch(void* const* d_in, const int* in_sizes, int n_in,
                              void* d_out, int out_size, void* d_ws, size_t ws_size,
                              hipStream_t stream) {
  const float* x  = (const float*)d_in[0];
  const float* Wq = (const float*)d_in[1];
  const float* Wk = (const float*)d_in[2];
  const float* Wv = (const float*)d_in[3];
  const float* Wo = (const float*)d_in[4];
  float* Y = (float*)d_out;

  const size_t qkv_elems = (size_t)BATCH * SEQ * HDIM;       // 1M
  const size_t w_elems   = (size_t)HDIM * HID;               // 64K
  unsigned short* Q     = (unsigned short*)d_ws;
  unsigned short* K     = Q + qkv_elems;
  unsigned short* Vt    = K + qkv_elems;
  unsigned short* O     = Vt + qkv_elems;
  unsigned short* Wqb   = O + qkv_elems;
  unsigned short* Wkb   = Wqb + w_elems;
  unsigned short* Wvb   = Wkb + w_elems;
  unsigned short* Wob   = Wvb + w_elems;
  unsigned short* Opart = Wob + w_elems;                      // 2048 slots x 4096 bf16
  float2*         Ml    = (float2*)(Opart + (size_t)2048 * 4096);  // 128K float2
  // total ws use ~26 MB

  convert_w   <<<1024,               256, 0, stream>>>(Wq, Wk, Wv, Wo, Wqb, Wkb, Wvb, Wob);
  qkv_proj    <<<1024,                64, 0, stream>>>(x, Wqb, Wkb, Wvb, Q, K, Vt);
  flash_splitk<<<dim3(64, 4, NCMAX), 256, 0, stream>>>(Q, K, Vt, O, Opart, Ml);
  merge_splitk<<<dim3(64, 4),        256, 0, stream>>>(Opart, Ml, O);
  out_proj    <<<dim3(16, 256),      256, 0, stream>>>(O, Wob, Y);
}

// Round 6
// 239.198 us; speedup vs baseline: 1.0208x; 1.0208x over previous
//
#include <hip/hip_runtime.h>
#include <hip/hip_bf16.h>

// SingleHeadAttention: B=4, S=4096, H=1024, D=64. fp32 I/O, bf16 MFMA compute.
//
// k0: convert Wq/Wk/Wv/Wo fp32 -> bf16 (ws)
// k1: fused QKV proj, m97-style: global_load_lds staged x (fp32, XOR-swizzled),
//     512 blocks x 256 thr (2 blocks/CU), wave=(row-tile, n-half), 3z fused.
// k2: split-K causal flash: 512-key chunks (CHT=8), reg-prefetch double buffer
// k3: merge partials (qb >= 8)
// k4: Y = O @ Wo^T (fp32 out)

typedef __attribute__((ext_vector_type(8))) __bf16 bf16x8;
typedef __attribute__((ext_vector_type(4))) float f32x4;

#define BATCH 4
#define SEQ   4096
#define HID   1024
#define HDIM  64
#define CHT   8           // 64-key tiles per split-K chunk
#define NCMAX 8           // max chunks per Q-tile

__device__ __forceinline__ unsigned short f2bf(float f) {
  unsigned u = __builtin_bit_cast(unsigned, f);
  u += 0x7fffu + ((u >> 16) & 1u);          // RTN
  return (unsigned short)(u >> 16);
}
__device__ __forceinline__ float bf2f(unsigned short u) {
  unsigned v = ((unsigned)u) << 16;
  return __builtin_bit_cast(float, v);
}
__device__ __forceinline__ __bf16 f2bf16(float f) {
  unsigned short us = f2bf(f);
  return __builtin_bit_cast(__bf16, us);
}
__device__ __forceinline__ bf16x8 pack8(f32x4 a, f32x4 b) {
  bf16x8 r;
  r[0] = f2bf16(a[0]); r[1] = f2bf16(a[1]); r[2] = f2bf16(a[2]); r[3] = f2bf16(a[3]);
  r[4] = f2bf16(b[0]); r[5] = f2bf16(b[1]); r[6] = f2bf16(b[2]); r[7] = f2bf16(b[3]);
  return r;
}

// ---------------- k0: weight conversion ----------------
__global__ __launch_bounds__(256) void convert_w(
    const float* __restrict__ Wq, const float* __restrict__ Wk,
    const float* __restrict__ Wv, const float* __restrict__ Wo,
    unsigned short* __restrict__ q, unsigned short* __restrict__ k,
    unsigned short* __restrict__ v, unsigned short* __restrict__ o) {
  const int gid = blockIdx.x * 256 + threadIdx.x;
  const int mat = gid >> 16, idx = gid & 0xFFFF;
  const float* s = (mat == 0) ? Wq : (mat == 1) ? Wk : (mat == 2) ? Wv : Wo;
  unsigned short* d = (mat == 0) ? q : (mat == 1) ? k : (mat == 2) ? v : o;
  d[idx] = f2bf(s[idx]);
}

// ---------------- k1: fused QKV projection (LDS-staged x) ----------------
// grid 512 x 256 thr. Block = 32 rows. Wave w: row-tile rt=w>>1, n-half nh=w&1.
// x tile (32 rows x 32 k, fp32) staged via global_load_lds, double-buffered.
// LDS content is XOR-swizzled per 16B chunk: LDS[row][p] = x chunk p^(row&7).
__global__ __launch_bounds__(256) void qkv_proj(
    const float* __restrict__ x,
    const unsigned short* __restrict__ Wqb,
    const unsigned short* __restrict__ Wkb,
    const unsigned short* __restrict__ Wvb,
    unsigned short* __restrict__ Q,
    unsigned short* __restrict__ K,
    unsigned short* __restrict__ Vt) {
  const int mb   = blockIdx.x;          // 32-row tile
  const int tid  = threadIdx.x;
  const int lane = tid & 63;
  const int wave = tid >> 6;
  const int quad = lane >> 4;
  const int l15  = lane & 15;
  const int rt   = wave >> 1;           // 0,1
  const int nh   = wave & 1;            // 0,1
  const int ar   = rt * 16 + l15;       // local row this lane reads for A
  const int row0 = mb * 32 + rt * 16;

  __shared__ float xs[2][32 * 32];      // [buf][row*32 + k], swizzled chunks

  const unsigned short* Ws[3] = {Wqb, Wkb, Wvb};

  f32x4 acc[3][2];
  const f32x4 zero = {0.f, 0.f, 0.f, 0.f};
#pragma unroll
  for (int z = 0; z < 3; ++z)
#pragma unroll
    for (int n2 = 0; n2 < 2; ++n2) acc[z][n2] = zero;

  // staging source: row = tid>>3, chunk = (tid&7) ^ (row&7)  (4 floats/chunk)
  const int srow   = tid >> 3;
  const int schunk = (tid & 7) ^ (srow & 7);
  const float* sgp = x + (size_t)(mb * 32 + srow) * HID + schunk * 4;
  // wave-uniform LDS dest base: lane writes base + lane*16
  float* lb0 = &xs[0][wave * 256];
  float* lb1 = &xs[1][wave * 256];

  // a-frag LDS read offsets (floats), XOR-swizzled positions
  const int ra0 = ar * 32 + ((2 * quad)     ^ (ar & 7)) * 4;
  const int ra1 = ar * 32 + ((2 * quad + 1) ^ (ar & 7)) * 4;

  // prologue: stage tile kk=0 into buf 0
  __builtin_amdgcn_global_load_lds(
      (const __attribute__((address_space(1))) void*)sgp,
      (__attribute__((address_space(3))) void*)lb0, 16, 0, 0);

  for (int kk = 0; kk < HID; kk += 32) {
    const int buf = (kk >> 5) & 1;
    __syncthreads();                    // drains vmcnt -> tile kk visible
    if (kk + 32 < HID) {                // stage next tile into other buffer
      __builtin_amdgcn_global_load_lds(
          (const __attribute__((address_space(1))) void*)(sgp + kk + 32),
          (__attribute__((address_space(3))) void*)(buf ? lb0 : lb1), 16, 0, 0);
    }
    // a-frag: 8 fp32 from LDS, cvt to bf16
    f32x4 alo = *reinterpret_cast<const f32x4*>(&xs[buf][ra0]);
    f32x4 ahi = *reinterpret_cast<const f32x4*>(&xs[buf][ra1]);
    bf16x8 a = pack8(alo, ahi);
#pragma unroll
    for (int z = 0; z < 3; ++z)
#pragma unroll
      for (int n2 = 0; n2 < 2; ++n2) {
        const int col = nh * 32 + n2 * 16 + l15;
        bf16x8 b = *reinterpret_cast<const bf16x8*>(Ws[z] + (size_t)col * HID + kk + quad * 8);
        acc[z][n2] = __builtin_amdgcn_mfma_f32_16x16x32_bf16(a, b, acc[z][n2], 0, 0, 0);
      }
  }

  // epilogue: C layout col=l15(+offsets), row=quad*4+r
#pragma unroll
  for (int z = 0; z < 2; ++z) {
    unsigned short* Out = (z == 0) ? Q : K;
#pragma unroll
    for (int n2 = 0; n2 < 2; ++n2)
#pragma unroll
      for (int r = 0; r < 4; ++r) {
        const int row = row0 + quad * 4 + r;
        const int col = nh * 32 + n2 * 16 + l15;
        Out[(size_t)row * HDIM + col] = f2bf(acc[z][n2][r]);
      }
  }
#pragma unroll
  for (int n2 = 0; n2 < 2; ++n2)
#pragma unroll
    for (int r = 0; r < 4; ++r) {
      const int row = row0 + quad * 4 + r;          // global seq index
      const int col = nh * 32 + n2 * 16 + l15;      // dim
      const int bb = row >> 12, sl = row & 4095;
      Vt[(size_t)bb * HDIM * SEQ + (size_t)col * SEQ + sl] = f2bf(acc[2][n2][r]);
    }
}

// ---------------- k2: split-K causal flash, reg-prefetch dbuf ----------------
#define LSTR 72   // 64 + 8 pad (16B-aligned rows)

__global__ __launch_bounds__(256) void flash_splitk(
    const unsigned short* __restrict__ Qg,
    const unsigned short* __restrict__ Kg,
    const unsigned short* __restrict__ Vt,
    unsigned short* __restrict__ Og,
    unsigned short* __restrict__ Opart,
    float2* __restrict__ Ml) {
  const int qb = blockIdx.x;
  const int b  = blockIdx.y;
  const int c  = blockIdx.z;
  const int nc = (qb >> 3) + 1;          // ceil((qb+1)/CHT) for CHT=8
  if (c >= nc) return;
  const int j0 = c * CHT;
  const int j1 = min(j0 + CHT, qb + 1);

  const int tid  = threadIdx.x;
  const int lane = tid & 63;
  const int wave = tid >> 6;
  const int quad = lane >> 4;
  const int l15  = lane & 15;

  __shared__ unsigned short kt[64 * LSTR];       // K tile [key][dim]
  __shared__ unsigned short vt[64 * LSTR];       // V tile [dim][key]
  __shared__ unsigned short pt[4][16 * LSTR];    // per-wave P [qrow][key]

  const size_t base  = (size_t)b * SEQ * HDIM;
  const size_t baseT = (size_t)b * HDIM * SEQ;
  const int qrow0 = qb * 64 + wave * 16;

  bf16x8 aq[2];
  {
    const unsigned short* qp = Qg + base + (size_t)(qrow0 + l15) * HDIM + quad * 8;
    aq[0] = *reinterpret_cast<const bf16x8*>(qp);
    aq[1] = *reinterpret_cast<const bf16x8*>(qp + 32);
  }

  f32x4 o[4];
  const f32x4 zero = {0.f, 0.f, 0.f, 0.f};
#pragma unroll
  for (int n = 0; n < 4; ++n) o[n] = zero;
  float m_i[4], l_i[4];
#pragma unroll
  for (int r = 0; r < 4; ++r) { m_i[r] = -__builtin_inff(); l_i[r] = 0.f; }

  unsigned short* pw = pt[wave];
  const int srow = tid >> 2, sc0 = (tid & 3) * 16;   // staging coords
  const unsigned short* kb = Kg + base;
  const unsigned short* vb = Vt + baseT;

  // softmax scale folded into exp2: p = 2^(s*C - m*C),  C = 0.125*log2(e)
  const float C = 0.125f * 1.44269504f;

  // prologue: stage tile j0
  uint4 pk0, pk1, pv0, pv1;
  {
    const uint4* kp = reinterpret_cast<const uint4*>(kb + (size_t)(j0 * 64 + srow) * HDIM + sc0);
    pk0 = kp[0]; pk1 = kp[1];
    const uint4* vp = reinterpret_cast<const uint4*>(vb + (size_t)srow * SEQ + j0 * 64 + sc0);
    pv0 = vp[0]; pv1 = vp[1];
    *reinterpret_cast<uint4*>(&kt[srow * LSTR + sc0])     = pk0;
    *reinterpret_cast<uint4*>(&kt[srow * LSTR + sc0 + 8]) = pk1;
    *reinterpret_cast<uint4*>(&vt[srow * LSTR + sc0])     = pv0;
    *reinterpret_cast<uint4*>(&vt[srow * LSTR + sc0 + 8]) = pv1;
  }

  for (int j = j0; j < j1; ++j) {
    __syncthreads();                       // publish LDS tile j
    const bool pre = (j + 1 < j1);
    if (pre) {                             // issue loads for tile j+1 now
      const uint4* kp = reinterpret_cast<const uint4*>(kb + (size_t)((j + 1) * 64 + srow) * HDIM + sc0);
      pk0 = kp[0]; pk1 = kp[1];
      const uint4* vp = reinterpret_cast<const uint4*>(vb + (size_t)srow * SEQ + (j + 1) * 64 + sc0);
      pv0 = vp[0]; pv1 = vp[1];
    }

    f32x4 s[4];
#pragma unroll
    for (int n = 0; n < 4; ++n) s[n] = zero;
#pragma unroll
    for (int ks = 0; ks < 2; ++ks) {
#pragma unroll
      for (int n = 0; n < 4; ++n) {
        bf16x8 bk = *reinterpret_cast<const bf16x8*>(&kt[(n * 16 + l15) * LSTR + ks * 32 + quad * 8]);
        s[n] = __builtin_amdgcn_mfma_f32_16x16x32_bf16(aq[ks], bk, s[n], 0, 0, 0);
      }
    }

    if (j == qb) {                         // causal mask (raw-score units)
#pragma unroll
      for (int n = 0; n < 4; ++n) {
        const int col = n * 16 + l15;
#pragma unroll
        for (int r = 0; r < 4; ++r) {
          const int rowl = wave * 16 + quad * 4 + r;
          if (col > rowl) s[n][r] = -__builtin_inff();
        }
      }
    }

    float mnew[4], alpha[4], mC[4];
#pragma unroll
    for (int r = 0; r < 4; ++r) {
      float v = fmaxf(fmaxf(s[0][r], s[1][r]), fmaxf(s[2][r], s[3][r]));
#pragma unroll
      for (int off = 1; off < 16; off <<= 1) v = fmaxf(v, __shfl_xor(v, off, 64));
      mnew[r]  = fmaxf(m_i[r], v);
      alpha[r] = __builtin_amdgcn_exp2f((m_i[r] - mnew[r]) * C);
      mC[r]    = mnew[r] * C;
    }
    float p[4][4];
#pragma unroll
    for (int n = 0; n < 4; ++n)
#pragma unroll
      for (int r = 0; r < 4; ++r)
        p[n][r] = __builtin_amdgcn_exp2f(__builtin_fmaf(s[n][r], C, -mC[r]));
#pragma unroll
    for (int r = 0; r < 4; ++r) {
      float v = (p[0][r] + p[1][r]) + (p[2][r] + p[3][r]);
#pragma unroll
      for (int off = 1; off < 16; off <<= 1) v += __shfl_xor(v, off, 64);
      l_i[r] = l_i[r] * alpha[r] + v;
      m_i[r] = mnew[r];
    }
#pragma unroll
    for (int n = 0; n < 4; ++n)
#pragma unroll
      for (int r = 0; r < 4; ++r) o[n][r] *= alpha[r];

#pragma unroll
    for (int n = 0; n < 4; ++n)
#pragma unroll
      for (int r = 0; r < 4; ++r)
        pw[(quad * 4 + r) * LSTR + n * 16 + l15] = f2bf(p[n][r]);

#pragma unroll
    for (int ks = 0; ks < 2; ++ks) {
      bf16x8 ap = *reinterpret_cast<const bf16x8*>(&pw[l15 * LSTR + ks * 32 + quad * 8]);
#pragma unroll
      for (int n = 0; n < 4; ++n) {
        bf16x8 bv = *reinterpret_cast<const bf16x8*>(&vt[(n * 16 + l15) * LSTR + ks * 32 + quad * 8]);
        o[n] = __builtin_amdgcn_mfma_f32_16x16x32_bf16(ap, bv, o[n], 0, 0, 0);
      }
    }

    __syncthreads();                       // all waves done reading kt/vt
    if (pre) {                             // drain prefetch into LDS
      *reinterpret_cast<uint4*>(&kt[srow * LSTR + sc0])     = pk0;
      *reinterpret_cast<uint4*>(&kt[srow * LSTR + sc0 + 8]) = pk1;
      *reinterpret_cast<uint4*>(&vt[srow * LSTR + sc0])     = pv0;
      *reinterpret_cast<uint4*>(&vt[srow * LSTR + sc0 + 8]) = pv1;
    }
  }

  if (nc == 1) {
#pragma unroll
    for (int n = 0; n < 4; ++n)
#pragma unroll
      for (int r = 0; r < 4; ++r) {
        const int row = qrow0 + quad * 4 + r;
        const int col = n * 16 + l15;
        Og[base + (size_t)row * HDIM + col] = f2bf(o[n][r] / l_i[r]);
      }
  } else {
    const int slot = ((b * 64 + qb) << 3) + c;
#pragma unroll
    for (int n = 0; n < 4; ++n)
#pragma unroll
      for (int r = 0; r < 4; ++r) {
        const int rowl = wave * 16 + quad * 4 + r;
        const int col  = n * 16 + l15;
        Opart[(size_t)slot * 4096 + rowl * 64 + col] = f2bf(o[n][r]);
      }
    if (l15 == 0) {
#pragma unroll
      for (int r = 0; r < 4; ++r) {
        const int rowl = wave * 16 + quad * 4 + r;
        Ml[slot * 64 + rowl] = make_float2(m_i[r], l_i[r]);
      }
    }
  }
}

// ---------------- k3: merge split-K partials (qb >= 8) ----------------
__global__ __launch_bounds__(256) void merge_splitk(
    const unsigned short* __restrict__ Opart,
    const float2* __restrict__ Ml,
    unsigned short* __restrict__ Og) {
  const int qb = blockIdx.x;
  if (qb < CHT) return;
  const int b  = blockIdx.y;
  const int nc = (qb >> 3) + 1;
  const int row = threadIdx.x >> 2;
  const int cg  = (threadIdx.x & 3) * 16;
  const int slot0 = (b * 64 + qb) << 3;

  float m[NCMAX], l[NCMAX];
  float M = -__builtin_inff();
  for (int c = 0; c < nc; ++c) {
    float2 ml = Ml[(slot0 + c) * 64 + row];
    m[c] = ml.x; l[c] = ml.y;
    M = fmaxf(M, m[c]);
  }
  const float C = 0.125f * 1.44269504f;
  float L = 0.f, acc[16];
#pragma unroll
  for (int i = 0; i < 16; ++i) acc[i] = 0.f;
  for (int c = 0; c < nc; ++c) {
    const float w = __builtin_amdgcn_exp2f((m[c] - M) * C);
    L += w * l[c];
    const unsigned short* p = Opart + (size_t)(slot0 + c) * 4096 + row * 64 + cg;
    uint4 u0 = *reinterpret_cast<const uint4*>(p);
    uint4 u1 = *reinterpret_cast<const uint4*>(p + 8);
    const unsigned* uu = &u0.x;
#pragma unroll
    for (int i = 0; i < 4; ++i) {
      acc[2 * i]     += w * bf2f((unsigned short)(uu[i] & 0xFFFF));
      acc[2 * i + 1] += w * bf2f((unsigned short)(uu[i] >> 16));
    }
    const unsigned* vv = &u1.x;
#pragma unroll
    for (int i = 0; i < 4; ++i) {
      acc[8 + 2 * i]     += w * bf2f((unsigned short)(vv[i] & 0xFFFF));
      acc[8 + 2 * i + 1] += w * bf2f((unsigned short)(vv[i] >> 16));
    }
  }
  const float inv = 1.f / L;
  uint4 o0, o1;
  unsigned* po = &o0.x;
#pragma unroll
  for (int i = 0; i < 4; ++i)
    po[i] = (unsigned)f2bf(acc[2 * i] * inv) | ((unsigned)f2bf(acc[2 * i + 1] * inv) << 16);
  unsigned* p1 = &o1.x;
#pragma unroll
  for (int i = 0; i < 4; ++i)
    p1[i] = (unsigned)f2bf(acc[8 + 2 * i] * inv) | ((unsigned)f2bf(acc[8 + 2 * i + 1] * inv) << 16);
  unsigned short* dst = Og + (size_t)b * SEQ * HDIM + (size_t)(qb * 64 + row) * HDIM + cg;
  *reinterpret_cast<uint4*>(dst)     = o0;
  *reinterpret_cast<uint4*>(dst + 8) = o1;
}

// ---------------- k4: output projection Y = O @ Wo^T (fp32 out) ----------------
__global__ __launch_bounds__(256) void out_proj(
    const unsigned short* __restrict__ O,
    const unsigned short* __restrict__ Wob,
    float* __restrict__ Y) {
  const int nb   = blockIdx.x;
  const int mb   = blockIdx.y;
  const int lane = threadIdx.x & 63;
  const int wave = threadIdx.x >> 6;
  const int quad = lane >> 4;
  const int l15  = lane & 15;
  const int row0 = mb * 64 + wave * 16;

  f32x4 acc[4];
  const f32x4 zero = {0.f, 0.f, 0.f, 0.f};
#pragma unroll
  for (int n = 0; n < 4; ++n) acc[n] = zero;

  const unsigned short* op = O + (size_t)(row0 + l15) * HDIM + quad * 8;
  bf16x8 a0 = *reinterpret_cast<const bf16x8*>(op);
  bf16x8 a1 = *reinterpret_cast<const bf16x8*>(op + 32);
#pragma unroll
  for (int n = 0; n < 4; ++n) {
    const int col = nb * 64 + n * 16 + l15;
    const unsigned short* wp = Wob + (size_t)col * HDIM + quad * 8;
    bf16x8 b0 = *reinterpret_cast<const bf16x8*>(wp);
    bf16x8 b1 = *reinterpret_cast<const bf16x8*>(wp + 32);
    acc[n] = __builtin_amdgcn_mfma_f32_16x16x32_bf16(a0, b0, acc[n], 0, 0, 0);
    acc[n] = __builtin_amdgcn_mfma_f32_16x16x32_bf16(a1, b1, acc[n], 0, 0, 0);
  }
#pragma unroll
  for (int n = 0; n < 4; ++n)
#pragma unroll
    for (int r = 0; r < 4; ++r) {
      const int row = row0 + quad * 4 + r;
      const int col = nb * 64 + n * 16 + l15;
      Y[(size_t)row * HID + col] = acc[n][r];
    }
}

extern "C" void kernel_launch(void* const* d_in, const int* in_sizes, int n_in,
                              void* d_out, int out_size, void* d_ws, size_t ws_size,
                              hipStream_t stream) {
  const float* x  = (const float*)d_in[0];
  const float* Wq = (const float*)d_in[1];
  const float* Wk = (const float*)d_in[2];
  const float* Wv = (const float*)d_in[3];
  const float* Wo = (const float*)d_in[4];
  float* Y = (float*)d_out;

  const size_t qkv_elems = (size_t)BATCH * SEQ * HDIM;       // 1M
  const size_t w_elems   = (size_t)HDIM * HID;               // 64K
  unsigned short* Q     = (unsigned short*)d_ws;
  unsigned short* K     = Q + qkv_elems;
  unsigned short* Vt    = K + qkv_elems;
  unsigned short* O     = Vt + qkv_elems;
  unsigned short* Wqb   = O + qkv_elems;
  unsigned short* Wkb   = Wqb + w_elems;
  unsigned short* Wvb   = Wkb + w_elems;
  unsigned short* Wob   = Wvb + w_elems;
  unsigned short* Opart = Wob + w_elems;                      // 2048 slots x 4096 bf16
  float2*         Ml    = (float2*)(Opart + (size_t)2048 * 4096);  // 128K float2
  // total ws use ~26 MB

  convert_w   <<<1024,               256, 0, stream>>>(Wq, Wk, Wv, Wo, Wqb, Wkb, Wvb, Wob);
  qkv_proj    <<<512,                256, 0, stream>>>(x, Wqb, Wkb, Wvb, Q, K, Vt);
  flash_splitk<<<dim3(64, 4, NCMAX), 256, 0, stream>>>(Q, K, Vt, O, Opart, Ml);
  merge_splitk<<<dim3(64, 4),        256, 0, stream>>>(Opart, Ml, O);
  out_proj    <<<dim3(16, 256),      256, 0, stream>>>(O, Wob, Y);
}